// Round 1
// 163.227 us; speedup vs baseline: 1.1298x; 1.1298x over previous
//
#include <hip/hip_runtime.h>

#define BATCH 512
#define SEQ   512
#define VOCAB 1000
#define EMB   100
#define UNITS 64

typedef float v2f __attribute__((ext_vector_type(2)));
typedef float v4f __attribute__((ext_vector_type(4)));
typedef int   v2i __attribute__((ext_vector_type(2)));

// ---------------------------------------------------------------------------
// Kernel 1: P[v][u] = sum_d emb[v][d] * Wxh[d][u] + b[u]   (VOCAB x UNITS)
// 4 vocab rows per 256-thread block (one row per wave), 4 independent FMA
// chains per lane: breaks the serial K=100 dependence (old: 1 chain, unroll 5,
// ~400-cyc dep chain + exposed cold-miss latency at 1 wave/SIMD).
// ---------------------------------------------------------------------------
__global__ __launch_bounds__(256) void proj_kernel(
    const float* __restrict__ emb, const float* __restrict__ Wxh,
    const float* __restrict__ bias, float* __restrict__ P) {
  const int v = blockIdx.x * 4 + (threadIdx.x >> 6);  // wave-uniform row
  const int u = threadIdx.x & 63;
  const float* e = emb + v * EMB;
  float a0 = 0.f, a1 = 0.f, a2 = 0.f, a3 = 0.f;
#pragma unroll
  for (int d = 0; d < EMB; d += 4) {
    a0 = fmaf(e[d + 0], Wxh[(d + 0) * UNITS + u], a0);
    a1 = fmaf(e[d + 1], Wxh[(d + 1) * UNITS + u], a1);
    a2 = fmaf(e[d + 2], Wxh[(d + 2) * UNITS + u], a2);
    a3 = fmaf(e[d + 3], Wxh[(d + 3) * UNITS + u], a3);
  }
  P[v * UNITS + u] = ((a0 + a1) + (a2 + a3)) + bias[u];
}

// ---------------------------------------------------------------------------
// Kernel 2: sequential scan, ONE wave per batch row.
//   h[j] <- tanh(P[tok_t][j] + sum_i h[i]*Whh[i][j])
//
// Split-K restructure of the step chain (old: every lane read ALL 64 h values
// = 16 ds_read_b128 = ~192 cyc DS issue on the serial chain):
//   lane l = (g = l>>5, m = l&31) reads only h[32g .. 32g+32) (8 ds_read_b128,
//   2-way bank alias = free) and computes TWO half-dot partials:
//     p0 = sum_{i in half g} h[i]*Whh[i][m]
//     p1 = sum_{i in half g} h[i]*Whh[i][m+32]
//   One v_permlane32_swap (dst.hi32 <-> src.lo32) + one add merges the halves
//   and the full y[l] lands exactly at lane l (h-layout preserved).
// tanh via exp2 + v_rcp (old: IEEE divide sequence, ~30 cyc on the chain).
// ---------------------------------------------------------------------------
__global__ __launch_bounds__(64)
__attribute__((amdgpu_waves_per_eu(1, 1)))
void scan_kernel(
    const int* __restrict__ tok, const float* __restrict__ P,
    const float* __restrict__ Whh, const float* __restrict__ Wout,
    const float* __restrict__ bout, float* __restrict__ out) {
  const int row  = blockIdx.x;
  const int lane = threadIdx.x;
  const int g    = lane >> 5;   // which half of the i-dimension this lane sums
  const int m    = lane & 31;

  __shared__ __align__(16) v4f hs4[UNITS / 4];  // 64 floats
  float* hsf = (float*)hs4;

  // Weights for the two partials, packed over i-pairs, pinned in VGPRs.
  //   wv0[k2] = {Whh[32g+2k2][m],    Whh[32g+2k2+1][m]}
  //   wv1[k2] = {Whh[32g+2k2][m+32], Whh[32g+2k2+1][m+32]}
  v2f wv0[UNITS / 4], wv1[UNITS / 4];
#pragma unroll
  for (int k2 = 0; k2 < UNITS / 4; ++k2) {
    const int i0 = 32 * g + 2 * k2;
    float ax = Whh[(i0 + 0) * UNITS + m];
    float ay = Whh[(i0 + 1) * UNITS + m];
    float bx = Whh[(i0 + 0) * UNITS + m + 32];
    float by = Whh[(i0 + 1) * UNITS + m + 32];
    asm volatile("" : "+v"(ax), "+v"(ay), "+v"(bx), "+v"(by));
    wv0[k2].x = ax; wv0[k2].y = ay;
    wv1[k2].x = bx; wv1[k2].y = by;
  }

  // All 512 tokens of this row, pre-scaled by UNITS (coalesced loads).
  int tokv[SEQ / 64];
  const int* trow = tok + (long)row * SEQ;
#pragma unroll
  for (int c = 0; c < SEQ / 64; ++c) {
    int t = trow[c * 64 + lane] * UNITS;
    asm volatile("" : "+v"(t));
    tokv[c] = t;
  }

  // h_0 = 0 (single wave: same-wave LDS ops are in-order, no barriers).
  hsf[lane] = 0.f;

  // Prefetch P row for t=0.
  int tk0 = __builtin_amdgcn_readlane(tokv[0], 0);
  float a = P[(long)tk0 + lane];

#pragma unroll
  for (int c = 0; c < SEQ / 64; ++c) {
#pragma unroll 2
    for (int tt = 0; tt < 64; ++tt) {
      float a_cur = a;
      // Prefetch next timestep's P row (consumed one full step later).
      int ntt = (tt + 1) & 63;
      int tkn = __builtin_amdgcn_readlane(tokv[c], ntt);
      a = P[(long)tkn + lane];

      // ---- Read only MY half of h: 8x ds_read_b128, back-to-back. ----
      v4f hq[UNITS / 8];
#pragma unroll
      for (int q = 0; q < UNITS / 8; ++q) hq[q] = hs4[(UNITS / 8) * g + q];

      // ---- Two half-dot partials, 4 independent 8-deep pk_fma chains. ----
      v2f p0a = {0.f, 0.f}, p0b = {0.f, 0.f};
      v2f p1a = {0.f, 0.f}, p1b = {0.f, 0.f};
#pragma unroll
      for (int q = 0; q < UNITS / 8; ++q) {
        v2f lo; lo.x = hq[q].x; lo.y = hq[q].y;
        v2f hi; hi.x = hq[q].z; hi.y = hq[q].w;
        p0a += lo * wv0[2 * q + 0];
        p0b += hi * wv0[2 * q + 1];
        p1a += lo * wv1[2 * q + 0];
        p1b += hi * wv1[2 * q + 1];
      }
      float s0 = (p0a.x + p0a.y) + (p0b.x + p0b.y);  // partial of y[m]
      float s1 = (p1a.x + p1a.y) + (p1b.x + p1b.y);  // partial of y[m+32]

      // ---- Merge halves: swap s0.hi32 <-> s1.lo32, then add. After the
      // swap, lane l holds both half-partials of output l. ----
#if __has_builtin(__builtin_amdgcn_permlane32_swap)
      v2i sw = __builtin_amdgcn_permlane32_swap(
          __float_as_int(s0), __float_as_int(s1), false, false);
      float y = __int_as_float(sw[0]) + __int_as_float(sw[1]) + a_cur;
#else
      float own = (lane & 32) ? s1 : s0;
      float oth = (lane & 32) ? s0 : s1;
      float y = own + __shfl_xor(oth, 32) + a_cur;
#endif

      // tanh(y) = 1 - 2*rcp(exp(2y)+1)  (saturation-safe at both extremes)
      float ex = __builtin_amdgcn_exp2f(y * 2.88539008177792681f);  // exp(2y)
      float h = fmaf(-2.f, __builtin_amdgcn_rcpf(ex + 1.f), 1.f);

      // Publish h for the next step (in-order DS pipe, no barrier needed).
      hsf[lane] = h;
    }
    if (c + 1 < SEQ / 64) {
      int tkb = __builtin_amdgcn_readlane(tokv[c + 1], 0);
      a = P[(long)tkb + lane];
    }
  }

  // out[row] = sigmoid(sum_j h[j]*Wout[j] + bout)
  float p = hsf[lane] * Wout[lane];
#pragma unroll
  for (int off = 32; off > 0; off >>= 1) p += __shfl_xor(p, off);
  if (lane == 0) out[row] = 1.f / (1.f + __expf(-(p + bout[0])));
}

extern "C" void kernel_launch(void* const* d_in, const int* in_sizes, int n_in,
                              void* d_out, int out_size, void* d_ws, size_t ws_size,
                              hipStream_t stream) {
  const int*   tok  = (const int*)  d_in[0];  // [BATCH, SEQ] int32
  const float* emb  = (const float*)d_in[1];  // [VOCAB, EMB]
  const float* Wxh  = (const float*)d_in[2];  // [EMB, UNITS]
  const float* Whh  = (const float*)d_in[3];  // [UNITS, UNITS]
  const float* bias = (const float*)d_in[4];  // [UNITS]
  const float* Wout = (const float*)d_in[5];  // [UNITS, 1]
  const float* bout = (const float*)d_in[6];  // [1]
  float* out = (float*)d_out;                 // [BATCH, 1] fp32

  float* P = (float*)d_ws;                    // VOCAB*UNITS fp32 = 256 KB

  proj_kernel<<<VOCAB / 4, 256, 0, stream>>>(emb, Wxh, bias, P);
  scan_kernel<<<BATCH, 64, 0, stream>>>(tok, P, Whh, Wout, bout, out);
}